// Round 4
// baseline (116.373 us; speedup 1.0000x reference)
//
#include <hip/hip_runtime.h>
#include <stdint.h>

#define IN_F 4096
#define OUT_F 4096
#define M_ROWS 4096   // B*S
#define BM 256
#define BN 128
#define BK 64
#define N_TILES_N 32  // OUT_F/BN
#define N_TILES_M 16  // M_ROWS/BM

typedef __attribute__((ext_vector_type(8))) short bf16x8;
typedef __attribute__((ext_vector_type(4))) float f32x4;
typedef __attribute__((ext_vector_type(4))) float f4;
typedef __attribute__((ext_vector_type(8))) unsigned short u16x8;

__device__ __forceinline__ unsigned short f32_to_bf16_rne(float f) {
    uint32_t u = __float_as_uint(f);
    u += 0x7FFFu + ((u >> 16) & 1u);
    return (unsigned short)(u >> 16);
}

// ---- merged prepass: x fp32->bf16 (blocks [0,8192)), W expand (blocks [8192,16384)) ----
__global__ __launch_bounds__(256) void prep_kernel(const float* __restrict__ x,
                                                   const float* __restrict__ wsrc,
                                                   unsigned short* __restrict__ xb,
                                                   unsigned short* __restrict__ wb) {
    int b = blockIdx.x;
    if (b < 8192) {
        size_t g = (size_t)b * 256 + threadIdx.x;   // one per 8 elems
        const f4* xp = (const f4*)x + g * 2;
        f4 a = xp[0], c = xp[1];
        u16x8 r;
        r[0] = f32_to_bf16_rne(a[0]); r[1] = f32_to_bf16_rne(a[1]);
        r[2] = f32_to_bf16_rne(a[2]); r[3] = f32_to_bf16_rne(a[3]);
        r[4] = f32_to_bf16_rne(c[0]); r[5] = f32_to_bf16_rne(c[1]);
        r[6] = f32_to_bf16_rne(c[2]); r[7] = f32_to_bf16_rne(c[3]);
        *((u16x8*)xb + g) = r;
    } else {
        size_t g = (size_t)(b - 8192) * 256 + threadIdx.x;
        int o  = (int)(g >> 9);
        int i0 = ((int)g & 511) << 3;
        int off = o * IN_F - ((o * (o - 1)) >> 1);
        u16x8 r;
#pragma unroll
        for (int j = 0; j < 8; ++j) {
            int i = i0 + j;
            float v = (i >= o) ? wsrc[off + (i - o)] : 0.0f;
            r[j] = f32_to_bf16_rne(v);
        }
        *((u16x8*)wb + g) = r;
    }
}

// ---- half-stage: 3 of 6 gload_lds per wave (A 2 quarters + B 1 half) ----
// LDS layout linear [row][slot(16B)x8]; global source col pre-swizzled: gslot = slot ^ (row&7)
__device__ __forceinline__ void stage_half(const unsigned short* __restrict__ A,
                                           const unsigned short* __restrict__ W,
                                           char* bufA, char* bufB,
                                           int m_base, int n_base, int k0,
                                           int wid, int lane, int half) {
    const int lrow  = lane >> 3;                 // 0..7
    const int gslot = (lane & 7) ^ lrow;         // pre-swizzled source slot
    const size_t coff = (size_t)k0 + (size_t)(gslot << 3);
#pragma unroll
    for (int q = 0; q < 2; ++q) {                // A: 16 rows per wave per half
        const int rb = (half * 2 + q) * 64 + wid * 8;
        const unsigned short* g = A + (size_t)(m_base + rb + lrow) * IN_F + coff;
        __builtin_amdgcn_global_load_lds(
            (const __attribute__((address_space(1))) void*)g,
            (__attribute__((address_space(3))) void*)(bufA + rb * 128), 16, 0, 0);
    }
    {                                            // B: 8 rows per wave per half
        const int rb = half * 64 + wid * 8;
        const unsigned short* g = W + (size_t)(n_base + rb + lrow) * IN_F + coff;
        __builtin_amdgcn_global_load_lds(
            (const __attribute__((address_space(1))) void*)g,
            (__attribute__((address_space(3))) void*)(bufB + rb * 128), 16, 0, 0);
    }
}

// ---- main GEMM: C[m][n] = sum_{k>=n_base} A[m][k]*W[n][k] + bias[n] ----
__global__ __launch_bounds__(512, 2) void tri_gemm_kernel(const unsigned short* __restrict__ A,
                                                          const unsigned short* __restrict__ W,
                                                          const float* __restrict__ bias,
                                                          float* __restrict__ C) {
    __shared__ __align__(16) char smem[3 * 49152];   // 3 x (A 32KB + B 16KB) = 144 KiB

    const int u = blockIdx.x;
    const int tile_n = u >> 4;          // longest-K jobs first (greedy LPT balance)
    const int tile_m = u & 15;
    const int m_base = tile_m * BM;
    const int n_base = tile_n * BN;
    const int nt = (IN_F - n_base) / BK;   // >= 2

    const int tid  = threadIdx.x;
    const int wid  = tid >> 6;
    const int lane = tid & 63;
    const int wr = wid >> 1;            // 0..3  (64-row band)
    const int wc = wid & 1;             // 0..1  (64-col band)
    const int frow = lane & 15;
    const int khalf = lane >> 4;        // 0..3 -> k slot offset

    char* pA0 = smem;               char* pB0 = smem + 32768;
    char* pA1 = smem + 49152;       char* pB1 = smem + 49152 + 32768;
    char* pA2 = smem + 2 * 49152;   char* pB2 = smem + 2 * 49152 + 32768;

    f32x4 acc[4][4];
#pragma unroll
    for (int i = 0; i < 4; ++i)
#pragma unroll
        for (int j = 0; j < 4; ++j) acc[i][j] = (f32x4){0.f, 0.f, 0.f, 0.f};

    // prologue: tiles 0 and 1 in flight (6 loads each per wave)
    stage_half(A, W, pA0, pB0, m_base, n_base, n_base,      wid, lane, 0);
    stage_half(A, W, pA0, pB0, m_base, n_base, n_base,      wid, lane, 1);
    stage_half(A, W, pA1, pB1, m_base, n_base, n_base + BK, wid, lane, 0);
    stage_half(A, W, pA1, pB1, m_base, n_base, n_base + BK, wid, lane, 1);

    for (int t = 0; t < nt; ++t) {
        // tile t fully resident (counted: tile t+1's 6 loads stay in flight)
        if (t + 1 < nt) { asm volatile("s_waitcnt vmcnt(6)" ::: "memory"); }
        else            { asm volatile("s_waitcnt vmcnt(0)" ::: "memory"); }
        __builtin_amdgcn_sched_barrier(0);
        __builtin_amdgcn_s_barrier();
        __builtin_amdgcn_sched_barrier(0);

        const int kpre = n_base + (t + 2) * BK;

        // ======== phase A: k-half 0 ========
        {
            bf16x8 af[4], bfr[4];
            const int slot = khalf ^ (frow & 7);          // ks=0
#pragma unroll
            for (int i = 0; i < 4; ++i)
                af[i] = *(const bf16x8*)(pA0 + (wr * 64 + i * 16 + frow) * 128 + slot * 16);
#pragma unroll
            for (int j = 0; j < 4; ++j)
                bfr[j] = *(const bf16x8*)(pB0 + (wc * 64 + j * 16 + frow) * 128 + slot * 16);

            if (t + 2 < nt)
                stage_half(A, W, pA2, pB2, m_base, n_base, kpre, wid, lane, 0);

            __builtin_amdgcn_s_barrier();                 // all reads+issues in before MFMA
            __builtin_amdgcn_s_setprio(1);
#pragma unroll
            for (int i = 0; i < 4; ++i)
#pragma unroll
                for (int j = 0; j < 4; ++j)
                    acc[i][j] = __builtin_amdgcn_mfma_f32_16x16x32_bf16(af[i], bfr[j], acc[i][j], 0, 0, 0);
            __builtin_amdgcn_s_setprio(0);
            __builtin_amdgcn_s_barrier();
        }

        // ======== phase B: k-half 1 ========
        {
            bf16x8 af[4], bfr[4];
            const int slot = (4 + khalf) ^ (frow & 7);    // ks=1
#pragma unroll
            for (int i = 0; i < 4; ++i)
                af[i] = *(const bf16x8*)(pA0 + (wr * 64 + i * 16 + frow) * 128 + slot * 16);
#pragma unroll
            for (int j = 0; j < 4; ++j)
                bfr[j] = *(const bf16x8*)(pB0 + (wc * 64 + j * 16 + frow) * 128 + slot * 16);

            if (t + 2 < nt)
                stage_half(A, W, pA2, pB2, m_base, n_base, kpre, wid, lane, 1);

            __builtin_amdgcn_s_barrier();
            __builtin_amdgcn_s_setprio(1);
#pragma unroll
            for (int i = 0; i < 4; ++i)
#pragma unroll
                for (int j = 0; j < 4; ++j)
                    acc[i][j] = __builtin_amdgcn_mfma_f32_16x16x32_bf16(af[i], bfr[j], acc[i][j], 0, 0, 0);
            __builtin_amdgcn_s_setprio(0);
            // no trailing barrier: next step's {vmcnt; s_barrier} covers the WAR window
        }

        // rotate buffers: t+1 becomes current, freed slot becomes issue target
        char* ta = pA0; pA0 = pA1; pA1 = pA2; pA2 = ta;
        char* tb = pB0; pB0 = pB1; pB1 = pB2; pB2 = tb;
    }

    // ---- epilogue: D layout col=lane&15, row=(lane>>4)*4+q ----
    const int col0 = n_base + wc * 64;
    const int row0 = m_base + wr * 64;
#pragma unroll
    for (int j = 0; j < 4; ++j) {
        const int col = col0 + j * 16 + frow;
        const float bv = bias[col];
#pragma unroll
        for (int i = 0; i < 4; ++i) {
            const int rbase = row0 + i * 16 + khalf * 4;
#pragma unroll
            for (int q = 0; q < 4; ++q) {
                C[(size_t)(rbase + q) * OUT_F + col] = acc[i][j][q] + bv;
            }
        }
    }
}

extern "C" void kernel_launch(void* const* d_in, const int* in_sizes, int n_in,
                              void* d_out, int out_size, void* d_ws, size_t ws_size,
                              hipStream_t stream) {
    const float* x    = (const float*)d_in[0];
    const float* w    = (const float*)d_in[1];
    const float* bias = (const float*)d_in[2];
    float* out = (float*)d_out;

    unsigned short* xb = (unsigned short*)d_ws;                  // 32 MiB bf16 x
    unsigned short* wb = xb + (size_t)M_ROWS * IN_F;             // 32 MiB bf16 dense W

    prep_kernel<<<16384, 256, 0, stream>>>(x, w, xb, wb);
    tri_gemm_kernel<<<N_TILES_M * N_TILES_N, 512, 0, stream>>>(xb, wb, bias, out);
}